// Round 1
// baseline (741.203 us; speedup 1.0000x reference)
//
#include <hip/hip_runtime.h>
#include <hip/hip_bf16.h>

#define Tt   16384
#define Dd   1024
#define Ee   8
#define CAP  2048
#define DFFf 4096

typedef __attribute__((ext_vector_type(8))) short bf16x8;
typedef __attribute__((ext_vector_type(4))) float f32x4;

__device__ __forceinline__ unsigned short f2bf(float f) {
  union { float f; unsigned u; } v; v.f = f;
  unsigned r = (v.u + 0x7FFFu + ((v.u >> 16) & 1u)) >> 16;
  return (unsigned short)r;
}

__device__ __forceinline__ float gelu_tanh(float x) {
  float z = 0.7978845608028654f * (x + 0.044715f * x * x * x);
  return 0.5f * x * (1.0f + tanhf(z));
}

__device__ __forceinline__ void gld16(const unsigned short* g, unsigned short* l) {
  __builtin_amdgcn_global_load_lds(
      (const __attribute__((address_space(1))) void*)g,
      (__attribute__((address_space(3))) void*)l,
      16, 0, 0);
}

// ---------------- gating: logits fp32, softmax, argmax ----------------
__global__ __launch_bounds__(256) void gating_kernel(
    const float* __restrict__ x, const float* __restrict__ wg,
    int* __restrict__ idx, float* __restrict__ gate, float* __restrict__ meP) {
  int tid = threadIdx.x, lane = tid & 63, w = tid >> 6;
  int t = blockIdx.x * 4 + w;
  const float* xr = x + (size_t)t * Dd;
  float p[8];
#pragma unroll
  for (int e2 = 0; e2 < 8; ++e2) p[e2] = 0.f;
#pragma unroll
  for (int i = 0; i < 16; ++i) {
    int j = lane + (i << 6);
    float xv = xr[j];
    const float4* wr = (const float4*)(wg + j * 8);
    float4 a = wr[0], b = wr[1];
    p[0] += xv * a.x; p[1] += xv * a.y; p[2] += xv * a.z; p[3] += xv * a.w;
    p[4] += xv * b.x; p[5] += xv * b.y; p[6] += xv * b.z; p[7] += xv * b.w;
  }
#pragma unroll
  for (int off = 32; off > 0; off >>= 1)
#pragma unroll
    for (int e2 = 0; e2 < 8; ++e2) p[e2] += __shfl_xor(p[e2], off);
  __shared__ float smG[4][8];
  if (lane == 0) {
    float mx = p[0]; int am = 0;
#pragma unroll
    for (int e2 = 1; e2 < 8; ++e2) if (p[e2] > mx) { mx = p[e2]; am = e2; }
    float s = 0.f, g2[8];
#pragma unroll
    for (int e2 = 0; e2 < 8; ++e2) { g2[e2] = __expf(p[e2] - mx); s += g2[e2]; }
    float inv = 1.f / s;
    idx[t] = am;
    gate[t] = g2[am] * inv;
#pragma unroll
    for (int e2 = 0; e2 < 8; ++e2) smG[w][e2] = g2[e2] * inv;
  }
  __syncthreads();
  if (tid < 8)
    meP[blockIdx.x * 8 + tid] = smG[0][tid] + smG[1][tid] + smG[2][tid] + smG[3][tid];
}

// ------------- scan: per-expert cumulative position + l_aux -------------
__global__ __launch_bounds__(512) void scan_kernel(
    const int* __restrict__ idx, int* __restrict__ pos, int* __restrict__ smap,
    const float* __restrict__ meP, int nblkG, float* __restrict__ laux_out) {
  int tid = threadIdx.x, lane = tid & 63, e = tid >> 6;
  int running = 0;
  for (int c = 0; c < Tt; c += 64) {
    int mi = idx[c + lane];
    bool pr = (mi == e);
    unsigned long long m = __ballot(pr);
    int p = running + __popcll(m & ((1ull << lane) - 1ull));
    if (pr) {
      pos[c + lane] = p;
      if (p < CAP) smap[e * CAP + p] = c + lane;
    }
    running += (int)__popcll(m);
  }
  __shared__ int scnt[8];
  __shared__ float smesum[8];
  __shared__ float red[512];
  if (lane == 0) scnt[e] = running;
  float part = 0.f;
  int ee = tid & 7, b0 = tid >> 3;
  for (int b = b0; b < nblkG; b += 64) part += meP[b * 8 + ee];
  red[tid] = part;
  __syncthreads();
  if (tid < 8) {
    float s = 0.f;
    for (int i = 0; i < 64; ++i) s += red[i * 8 + tid];
    smesum[tid] = s;
  }
  __syncthreads();
  if (tid == 0) {
    float l = 0.f;
    for (int q = 0; q < 8; ++q) l += smesum[q] * (float)scnt[q];
    laux_out[0] = l * 8.0f / ((float)Tt * (float)Tt);
  }
}

// ------------- transpose + cast fp32 -> bf16 (B^T weight layout) -------------
__global__ __launch_bounds__(256) void transpose_cast(
    const float* __restrict__ src, unsigned short* __restrict__ dst, int R, int Cn) {
  __shared__ float tile[64][65];
  int e = blockIdx.z;
  const float* s = src + (size_t)e * R * Cn;
  unsigned short* d = dst + (size_t)e * R * Cn;
  int c = threadIdx.x & 63;
  int r0 = threadIdx.x >> 6;
  int rb = blockIdx.y * 64, cb = blockIdx.x * 64;
#pragma unroll
  for (int i = 0; i < 16; ++i) {
    int r = r0 + i * 4;
    tile[r][c] = s[(size_t)(rb + r) * Cn + cb + c];
  }
  __syncthreads();
#pragma unroll
  for (int i = 0; i < 16; ++i) {
    int r = r0 + i * 4;
    d[(size_t)(cb + r) * R + rb + c] = f2bf(tile[c][r]);
  }
}

// ------------- gather + cast dispatched tokens -------------
__global__ __launch_bounds__(256) void build_xg(
    const float* __restrict__ x, const int* __restrict__ smap,
    unsigned short* __restrict__ Xg) {
  int row = blockIdx.x;
  int t = smap[row];
  int j = threadIdx.x;
  float4 v = make_float4(0.f, 0.f, 0.f, 0.f);
  if (t >= 0) v = ((const float4*)(x + (size_t)t * Dd))[j];
  ushort4 o;
  o.x = f2bf(v.x); o.y = f2bf(v.y); o.z = f2bf(v.z); o.w = f2bf(v.w);
  ((ushort4*)(Xg + (size_t)row * Dd))[j] = o;
}

// ------------- bf16 MFMA GEMM, B^T input (m97 128^2 structure) -------------
template <int DO_GELU, int OUT_BF16>
__global__ __launch_bounds__(256) void gemm_bt_kernel(
    const unsigned short* __restrict__ A,   // [E][M][K] bf16
    const unsigned short* __restrict__ BT,  // [E][N][K] bf16
    void* __restrict__ Cout,                // [E][M][N]
    int M, int N, int K) {
  __shared__ unsigned short lsA[128 * 32];
  __shared__ unsigned short lsB[128 * 32];
  int tid = threadIdx.x, lane = tid & 63, w = tid >> 6;
  int wm = w >> 1, wn = w & 1;
  int e = blockIdx.z;
  int bm = blockIdx.y, bn = blockIdx.x;
  const unsigned short* Ab = A + (size_t)e * M * K + (size_t)(bm * 128) * K;
  const unsigned short* Bb = BT + (size_t)e * N * K + (size_t)(bn * 128) * K;
  int row4 = tid >> 2;
  int kcol = (tid & 3) * 8;
  f32x4 acc[4][4];
#pragma unroll
  for (int m = 0; m < 4; ++m)
#pragma unroll
    for (int n = 0; n < 4; ++n) acc[m][n] = (f32x4){0.f, 0.f, 0.f, 0.f};

  for (int k0 = 0; k0 < K; k0 += 32) {
    const unsigned short* gA = Ab + (size_t)row4 * K + k0 + kcol;
    const unsigned short* gB = Bb + (size_t)row4 * K + k0 + kcol;
    gld16(gA, &lsA[tid * 8]);
    gld16(gA + (size_t)64 * K, &lsA[2048 + tid * 8]);
    gld16(gB, &lsB[tid * 8]);
    gld16(gB + (size_t)64 * K, &lsB[2048 + tid * 8]);
    __syncthreads();
    bf16x8 af[4], bfr[4];
#pragma unroll
    for (int m = 0; m < 4; ++m)
      af[m] = *(const bf16x8*)&lsA[(wm * 64 + m * 16 + (lane & 15)) * 32 + (lane >> 4) * 8];
#pragma unroll
    for (int n = 0; n < 4; ++n)
      bfr[n] = *(const bf16x8*)&lsB[(wn * 64 + n * 16 + (lane & 15)) * 32 + (lane >> 4) * 8];
#pragma unroll
    for (int m = 0; m < 4; ++m)
#pragma unroll
      for (int n = 0; n < 4; ++n)
        acc[m][n] = __builtin_amdgcn_mfma_f32_16x16x32_bf16(af[m], bfr[n], acc[m][n], 0, 0, 0);
    __syncthreads();
  }

  size_t cb = (size_t)e * M * N;
  int r0 = bm * 128 + wm * 64;
  int c0 = bn * 128 + wn * 64;
#pragma unroll
  for (int m = 0; m < 4; ++m) {
#pragma unroll
    for (int n = 0; n < 4; ++n) {
      int row = r0 + m * 16 + ((lane >> 4) << 2);
      int col = c0 + n * 16 + (lane & 15);
#pragma unroll
      for (int r = 0; r < 4; ++r) {
        float v = acc[m][n][r];
        if (DO_GELU) v = gelu_tanh(v);
        if (OUT_BF16)
          ((unsigned short*)Cout)[cb + (size_t)(row + r) * N + col] = f2bf(v);
        else
          ((float*)Cout)[cb + (size_t)(row + r) * N + col] = v;
      }
    }
  }
}

// ------------- combine: gather expert output, weight by gate -------------
__global__ __launch_bounds__(256) void combine_kernel(
    const float* __restrict__ eout, const int* __restrict__ idx,
    const int* __restrict__ pos, const float* __restrict__ gate,
    float* __restrict__ out) {
  int t = blockIdx.x;
  int e = idx[t], p = pos[t];
  float g = gate[t];
  int j = threadIdx.x;
  float4 v = make_float4(0.f, 0.f, 0.f, 0.f);
  if (p < CAP) {
    v = ((const float4*)(eout + ((size_t)e * CAP + p) * Dd))[j];
    v.x *= g; v.y *= g; v.z *= g; v.w *= g;
  }
  ((float4*)(out + (size_t)t * Dd))[j] = v;
}

extern "C" void kernel_launch(void* const* d_in, const int* in_sizes, int n_in,
                              void* d_out, int out_size, void* d_ws, size_t ws_size,
                              hipStream_t stream) {
  const float* x  = (const float*)d_in[0];
  const float* wg = (const float*)d_in[1];
  const float* w1 = (const float*)d_in[2];
  const float* w2 = (const float*)d_in[3];
  float* out = (float*)d_out;

  char* ws = (char*)d_ws;
  int*   idx  = (int*)(ws + 0);
  int*   pos  = (int*)(ws + 65536);
  float* gate = (float*)(ws + 131072);
  float* meP  = (float*)(ws + 196608);
  int*   smap = (int*)(ws + 327680);
  unsigned short* Xg  = (unsigned short*)(ws + 393216ull);
  unsigned short* W1T = (unsigned short*)(ws + 33947648ull);
  unsigned short* W2T = (unsigned short*)(ws + 101056512ull);
  unsigned short* H   = (unsigned short*)(ws + 168165376ull);
  float*          EOUT = (float*)(ws + 302383104ull);

  hipMemsetAsync(smap, 0xFF, Ee * CAP * 4, stream);
  gating_kernel<<<Tt / 4, 256, 0, stream>>>(x, wg, idx, gate, meP);
  scan_kernel<<<1, 512, 0, stream>>>(idx, pos, smap, meP, Tt / 4,
                                     out + (size_t)Tt * Dd);
  transpose_cast<<<dim3(DFFf / 64, Dd / 64, Ee), 256, 0, stream>>>(w1, W1T, Dd, DFFf);
  transpose_cast<<<dim3(Dd / 64, DFFf / 64, Ee), 256, 0, stream>>>(w2, W2T, DFFf, Dd);
  build_xg<<<Ee * CAP, 256, 0, stream>>>(x, smap, Xg);
  gemm_bt_kernel<1, 1><<<dim3(DFFf / 128, CAP / 128, Ee), 256, 0, stream>>>(
      Xg, W1T, (void*)H, CAP, DFFf, Dd);
  gemm_bt_kernel<0, 0><<<dim3(Dd / 128, CAP / 128, Ee), 256, 0, stream>>>(
      H, W2T, (void*)EOUT, CAP, Dd, DFFf);
  combine_kernel<<<Tt, 256, 0, stream>>>(EOUT, idx, pos, gate, out);
}

// Round 2
// 561.519 us; speedup vs baseline: 1.3200x; 1.3200x over previous
//
#include <hip/hip_runtime.h>
#include <hip/hip_bf16.h>

#define Tt   16384
#define Dd   1024
#define Ee   8
#define CAP  2048
#define DFFf 4096

typedef __attribute__((ext_vector_type(8))) short bf16x8;
typedef __attribute__((ext_vector_type(4))) float f32x4;

__device__ __forceinline__ unsigned short f2bf(float f) {
  union { float f; unsigned u; } v; v.f = f;
  unsigned r = (v.u + 0x7FFFu + ((v.u >> 16) & 1u)) >> 16;
  return (unsigned short)r;
}

__device__ __forceinline__ float gelu_tanh(float x) {
  float z = 0.7978845608028654f * (x + 0.044715f * x * x * x);
  return 0.5f * x * (1.0f + tanhf(z));
}

__device__ __forceinline__ void gld16(const unsigned short* g, unsigned short* l) {
  __builtin_amdgcn_global_load_lds(
      (const __attribute__((address_space(1))) void*)g,
      (__attribute__((address_space(3))) void*)l,
      16, 0, 0);
}

// ---------------- gating: logits fp32, softmax, argmax ----------------
__global__ __launch_bounds__(256) void gating_kernel(
    const float* __restrict__ x, const float* __restrict__ wg,
    int* __restrict__ idx, float* __restrict__ gate, float* __restrict__ meP) {
  int tid = threadIdx.x, lane = tid & 63, w = tid >> 6;
  int t = blockIdx.x * 4 + w;
  const float* xr = x + (size_t)t * Dd;
  float p[8];
#pragma unroll
  for (int e2 = 0; e2 < 8; ++e2) p[e2] = 0.f;
#pragma unroll
  for (int i = 0; i < 16; ++i) {
    int j = lane + (i << 6);
    float xv = xr[j];
    const float4* wr = (const float4*)(wg + j * 8);
    float4 a = wr[0], b = wr[1];
    p[0] += xv * a.x; p[1] += xv * a.y; p[2] += xv * a.z; p[3] += xv * a.w;
    p[4] += xv * b.x; p[5] += xv * b.y; p[6] += xv * b.z; p[7] += xv * b.w;
  }
#pragma unroll
  for (int off = 32; off > 0; off >>= 1)
#pragma unroll
    for (int e2 = 0; e2 < 8; ++e2) p[e2] += __shfl_xor(p[e2], off);
  __shared__ float smG[4][8];
  if (lane == 0) {
    float mx = p[0]; int am = 0;
#pragma unroll
    for (int e2 = 1; e2 < 8; ++e2) if (p[e2] > mx) { mx = p[e2]; am = e2; }
    float s = 0.f, g2[8];
#pragma unroll
    for (int e2 = 0; e2 < 8; ++e2) { g2[e2] = __expf(p[e2] - mx); s += g2[e2]; }
    float inv = 1.f / s;
    idx[t] = am;
    gate[t] = g2[am] * inv;
#pragma unroll
    for (int e2 = 0; e2 < 8; ++e2) smG[w][e2] = g2[e2] * inv;
  }
  __syncthreads();
  if (tid < 8)
    meP[blockIdx.x * 8 + tid] = smG[0][tid] + smG[1][tid] + smG[2][tid] + smG[3][tid];
}

// ------------- scan: per-expert cumulative position + l_aux -------------
__global__ __launch_bounds__(512) void scan_kernel(
    const int* __restrict__ idx, int* __restrict__ pos, int* __restrict__ smap,
    const float* __restrict__ meP, int nblkG, float* __restrict__ laux_out) {
  int tid = threadIdx.x, lane = tid & 63, e = tid >> 6;
  int running = 0;
  for (int c = 0; c < Tt; c += 64) {
    int mi = idx[c + lane];
    bool pr = (mi == e);
    unsigned long long m = __ballot(pr);
    int p = running + __popcll(m & ((1ull << lane) - 1ull));
    if (pr) {
      pos[c + lane] = p;
      if (p < CAP) smap[e * CAP + p] = c + lane;
    }
    running += (int)__popcll(m);
  }
  __shared__ int scnt[8];
  __shared__ float smesum[8];
  __shared__ float red[512];
  if (lane == 0) scnt[e] = running;
  float part = 0.f;
  int ee = tid & 7, b0 = tid >> 3;
  for (int b = b0; b < nblkG; b += 64) part += meP[b * 8 + ee];
  red[tid] = part;
  __syncthreads();
  if (tid < 8) {
    float s = 0.f;
    for (int i = 0; i < 64; ++i) s += red[i * 8 + tid];
    smesum[tid] = s;
  }
  __syncthreads();
  if (tid == 0) {
    float l = 0.f;
    for (int q = 0; q < 8; ++q) l += smesum[q] * (float)scnt[q];
    laux_out[0] = l * 8.0f / ((float)Tt * (float)Tt);
  }
}

// ------------- transpose + cast fp32 -> bf16 (B^T weight layout) -------------
__global__ __launch_bounds__(256) void transpose_cast(
    const float* __restrict__ src, unsigned short* __restrict__ dst, int R, int Cn) {
  __shared__ float tile[64][65];
  int e = blockIdx.z;
  const float* s = src + (size_t)e * R * Cn;
  unsigned short* d = dst + (size_t)e * R * Cn;
  int c = threadIdx.x & 63;
  int r0 = threadIdx.x >> 6;
  int rb = blockIdx.y * 64, cb = blockIdx.x * 64;
#pragma unroll
  for (int i = 0; i < 16; ++i) {
    int r = r0 + i * 4;
    tile[r][c] = s[(size_t)(rb + r) * Cn + cb + c];
  }
  __syncthreads();
#pragma unroll
  for (int i = 0; i < 16; ++i) {
    int r = r0 + i * 4;
    d[(size_t)(cb + r) * R + rb + c] = f2bf(tile[c][r]);
  }
}

// ------------- gather + cast dispatched tokens -------------
__global__ __launch_bounds__(256) void build_xg(
    const float* __restrict__ x, const int* __restrict__ smap,
    unsigned short* __restrict__ Xg) {
  int row = blockIdx.x;
  int t = smap[row];
  int j = threadIdx.x;
  float4 v = make_float4(0.f, 0.f, 0.f, 0.f);
  if (t >= 0) v = ((const float4*)(x + (size_t)t * Dd))[j];
  ushort4 o;
  o.x = f2bf(v.x); o.y = f2bf(v.y); o.z = f2bf(v.z); o.w = f2bf(v.w);
  ((ushort4*)(Xg + (size_t)row * Dd))[j] = o;
}

// ------------- 256^2-tile 4-phase bf16 MFMA GEMM (B^T), XOR-swizzled LDS -------------
// 512 threads = 8 waves (2M x 4N), per-wave 128x64 output, BK=64, double-buffered LDS.
template <int DO_GELU, int FUSE_COMBINE>
__global__ __launch_bounds__(512, 2) void gemm256_kernel(
    const unsigned short* __restrict__ A,   // [E][M][K] bf16
    const unsigned short* __restrict__ BT,  // [E][N][K] bf16
    unsigned short* __restrict__ Hout,      // [E][M][N] bf16 (GEMM1)
    const int* __restrict__ smap,           // [E][CAP] token map (GEMM2)
    const float* __restrict__ gate,         // [T]
    float* __restrict__ out,                // [T][D]
    int M, int N, int K) {
  __shared__ unsigned short lds[2][2][16384];  // [buf][A/B][256 rows x 64 k] 128 KiB
  int tid = threadIdx.x, lane = tid & 63, w = tid >> 6;
  int wm = w >> 2, wn = w & 3;

  // bijective XCD-aware swizzle over the whole grid (nwg % 8 == 0)
  int gx = gridDim.x, gy = gridDim.y;
  long gid = blockIdx.x + (long)gx * (blockIdx.y + (long)gy * blockIdx.z);
  int nT = gx * gy * (int)gridDim.z;
  int cpx = nT >> 3;
  int swz = (int)((gid & 7) * (long)cpx + (gid >> 3));
  int bn = swz % gx;
  int bm = (swz / gx) % gy;
  int e  = swz / (gx * gy);

  const unsigned short* Ab = A + ((size_t)e * M + (size_t)bm * 256) * K;
  const unsigned short* Bb = BT + ((size_t)e * N + (size_t)bn * 256) * K;

  // Stage a full 256x64 operand tile (32 KiB) into LDS region L.
  // Linear LDS dest (gload_lds requirement); swizzle applied by pre-swizzling
  // the global source: phys p holds logical p ^ (((p>>7)&7)<<4) (involution).
  auto stage_op = [&](const unsigned short* srcBase, unsigned short* L) {
#pragma unroll
    for (int q = 0; q < 4; ++q) {
      int p = q * 8192 + tid * 16;
      int lg = p ^ (((p >> 7) & 7) << 4);
      int row = lg >> 7;
      int cs = (lg & 127) >> 1;
      gld16(srcBase + (size_t)row * K + cs, (unsigned short*)((char*)L + p));
    }
  };
  // Read one MFMA fragment (8 bf16) at logical (row, kcol) with matching swizzle.
  auto frag = [&](const unsigned short* L, int row, int kc) -> bf16x8 {
    int byte = (row << 7) + (kc << 1);
    byte ^= (row & 7) << 4;
    return *(const bf16x8*)((const char*)L + byte);
  };

  f32x4 acc[2][4][4];
#pragma unroll
  for (int mh = 0; mh < 2; ++mh)
#pragma unroll
    for (int mi = 0; mi < 4; ++mi)
#pragma unroll
      for (int n = 0; n < 4; ++n) acc[mh][mi][n] = (f32x4){0.f, 0.f, 0.f, 0.f};

  int NT = K >> 6;
  stage_op(Ab, lds[0][0]);
  stage_op(Bb, lds[0][1]);
  asm volatile("s_waitcnt vmcnt(0)" ::: "memory");
  __builtin_amdgcn_s_barrier();

  int arow = wm * 128 + (lane & 15);
  int brow = wn * 64 + (lane & 15);
  int kcA = (lane >> 4) << 3;

  for (int t = 0; t < NT; ++t) {
    const unsigned short* LA = lds[t & 1][0];
    const unsigned short* LB = lds[t & 1][1];
    unsigned short* SA = lds[(t & 1) ^ 1][0];
    unsigned short* SB = lds[(t & 1) ^ 1][1];
    bool pf = (t + 1 < NT);
    int kn = (t + 1) << 6;
    bf16x8 a0[4], a1[4], b0[4], b1[4];
    // ---- phase 0: ksub0, m-half 0 ----
#pragma unroll
    for (int i = 0; i < 4; ++i) b0[i] = frag(LB, brow + i * 16, kcA);
#pragma unroll
    for (int i = 0; i < 4; ++i) a0[i] = frag(LA, arow + i * 16, kcA);
    if (pf) stage_op(Ab + kn, SA);
    __builtin_amdgcn_s_barrier();
    __builtin_amdgcn_s_setprio(1);
#pragma unroll
    for (int mi = 0; mi < 4; ++mi)
#pragma unroll
      for (int n = 0; n < 4; ++n)
        acc[0][mi][n] = __builtin_amdgcn_mfma_f32_16x16x32_bf16(a0[mi], b0[n], acc[0][mi][n], 0, 0, 0);
    __builtin_amdgcn_s_setprio(0);
    __builtin_amdgcn_s_barrier();
    // ---- phase 1: ksub1, m-half 0 ----
#pragma unroll
    for (int i = 0; i < 4; ++i) b1[i] = frag(LB, brow + i * 16, 32 + kcA);
#pragma unroll
    for (int i = 0; i < 4; ++i) a1[i] = frag(LA, arow + i * 16, 32 + kcA);
    if (pf) stage_op(Bb + kn, SB);
    __builtin_amdgcn_s_barrier();
    __builtin_amdgcn_s_setprio(1);
#pragma unroll
    for (int mi = 0; mi < 4; ++mi)
#pragma unroll
      for (int n = 0; n < 4; ++n)
        acc[0][mi][n] = __builtin_amdgcn_mfma_f32_16x16x32_bf16(a1[mi], b1[n], acc[0][mi][n], 0, 0, 0);
    __builtin_amdgcn_s_setprio(0);
    __builtin_amdgcn_s_barrier();
    // ---- phase 2: ksub0, m-half 1 ----
#pragma unroll
    for (int i = 0; i < 4; ++i) a0[i] = frag(LA, arow + 64 + i * 16, kcA);
    __builtin_amdgcn_s_barrier();
    __builtin_amdgcn_s_setprio(1);
#pragma unroll
    for (int mi = 0; mi < 4; ++mi)
#pragma unroll
      for (int n = 0; n < 4; ++n)
        acc[1][mi][n] = __builtin_amdgcn_mfma_f32_16x16x32_bf16(a0[mi], b0[n], acc[1][mi][n], 0, 0, 0);
    __builtin_amdgcn_s_setprio(0);
    __builtin_amdgcn_s_barrier();
    // ---- phase 3: ksub1, m-half 1 ----
#pragma unroll
    for (int i = 0; i < 4; ++i) a1[i] = frag(LA, arow + 64 + i * 16, 32 + kcA);
    __builtin_amdgcn_s_barrier();
    __builtin_amdgcn_s_setprio(1);
#pragma unroll
    for (int mi = 0; mi < 4; ++mi)
#pragma unroll
      for (int n = 0; n < 4; ++n)
        acc[1][mi][n] = __builtin_amdgcn_mfma_f32_16x16x32_bf16(a1[mi], b1[n], acc[1][mi][n], 0, 0, 0);
    __builtin_amdgcn_s_setprio(0);
    asm volatile("s_waitcnt vmcnt(0)" ::: "memory");
    __builtin_amdgcn_s_barrier();
  }

  // ---- epilogue ----
  int r0 = bm * 256 + wm * 128;
  int c0 = bn * 256 + wn * 64;
#pragma unroll
  for (int mh = 0; mh < 2; ++mh)
#pragma unroll
    for (int mi = 0; mi < 4; ++mi) {
      int rowb = r0 + mh * 64 + mi * 16 + ((lane >> 4) << 2);
#pragma unroll
      for (int r = 0; r < 4; ++r) {
        int row = rowb + r;
        if (DO_GELU) {
#pragma unroll
          for (int n = 0; n < 4; ++n) {
            int col = c0 + n * 16 + (lane & 15);
            Hout[((size_t)e * M + row) * N + col] = f2bf(gelu_tanh(acc[mh][mi][n][r]));
          }
        }
        if (FUSE_COMBINE) {
          int tkn = smap[e * CAP + row];
          if (tkn >= 0) {
            float g = gate[tkn];
#pragma unroll
            for (int n = 0; n < 4; ++n) {
              int col = c0 + n * 16 + (lane & 15);
              out[(size_t)tkn * Dd + col] = acc[mh][mi][n][r] * g;
            }
          }
        }
      }
    }
}

extern "C" void kernel_launch(void* const* d_in, const int* in_sizes, int n_in,
                              void* d_out, int out_size, void* d_ws, size_t ws_size,
                              hipStream_t stream) {
  const float* x  = (const float*)d_in[0];
  const float* wg = (const float*)d_in[1];
  const float* w1 = (const float*)d_in[2];
  const float* w2 = (const float*)d_in[3];
  float* out = (float*)d_out;

  char* ws = (char*)d_ws;
  int*   idx  = (int*)(ws + 0);
  int*   pos  = (int*)(ws + 65536);
  float* gate = (float*)(ws + 131072);
  float* meP  = (float*)(ws + 196608);
  int*   smap = (int*)(ws + 327680);
  unsigned short* Xg  = (unsigned short*)(ws + 393216ull);
  unsigned short* W1T = (unsigned short*)(ws + 33947648ull);
  unsigned short* W2T = (unsigned short*)(ws + 101056512ull);
  unsigned short* H   = (unsigned short*)(ws + 168165376ull);

  hipMemsetAsync(out, 0, (size_t)Tt * Dd * sizeof(float), stream);
  hipMemsetAsync(smap, 0xFF, Ee * CAP * 4, stream);
  gating_kernel<<<Tt / 4, 256, 0, stream>>>(x, wg, idx, gate, meP);
  scan_kernel<<<1, 512, 0, stream>>>(idx, pos, smap, meP, Tt / 4,
                                     out + (size_t)Tt * Dd);
  transpose_cast<<<dim3(DFFf / 64, Dd / 64, Ee), 256, 0, stream>>>(w1, W1T, Dd, DFFf);
  transpose_cast<<<dim3(Dd / 64, DFFf / 64, Ee), 256, 0, stream>>>(w2, W2T, DFFf, Dd);
  build_xg<<<Ee * CAP, 256, 0, stream>>>(x, smap, Xg);
  gemm256_kernel<1, 0><<<dim3(DFFf / 256, CAP / 256, Ee), 512, 0, stream>>>(
      Xg, W1T, H, nullptr, nullptr, nullptr, CAP, DFFf, Dd);
  gemm256_kernel<0, 1><<<dim3(Dd / 256, CAP / 256, Ee), 512, 0, stream>>>(
      H, W2T, nullptr, smap, gate, out, CAP, Dd, DFFf);
}

// Round 3
// 533.380 us; speedup vs baseline: 1.3896x; 1.0528x over previous
//
#include <hip/hip_runtime.h>
#include <hip/hip_bf16.h>

#define Tt   16384
#define Dd   1024
#define Ee   8
#define CAP  2048
#define DFFf 4096

typedef __attribute__((ext_vector_type(8))) short bf16x8;
typedef __attribute__((ext_vector_type(4))) float f32x4;

__device__ __forceinline__ unsigned short f2bf(float f) {
  union { float f; unsigned u; } v; v.f = f;
  unsigned r = (v.u + 0x7FFFu + ((v.u >> 16) & 1u)) >> 16;
  return (unsigned short)r;
}

__device__ __forceinline__ float gelu_tanh(float x) {
  float z = 0.7978845608028654f * (x + 0.044715f * x * x * x);
  float az = fabsf(z);
  float t = __expf(-2.0f * az);
  float th = (1.0f - t) / (1.0f + t);
  th = (z < 0.0f) ? -th : th;
  return 0.5f * x * (1.0f + th);
}

__device__ __forceinline__ void gld16(const unsigned short* g, unsigned short* l) {
  __builtin_amdgcn_global_load_lds(
      (const __attribute__((address_space(1))) void*)g,
      (__attribute__((address_space(3))) void*)l,
      16, 0, 0);
}

// ---------------- gating: logits fp32, softmax, argmax ----------------
__global__ __launch_bounds__(256) void gating_kernel(
    const float* __restrict__ x, const float* __restrict__ wg,
    int* __restrict__ idx, float* __restrict__ gate, float* __restrict__ meP) {
  int tid = threadIdx.x, lane = tid & 63, w = tid >> 6;
  int t = blockIdx.x * 4 + w;
  const float* xr = x + (size_t)t * Dd;
  float p[8];
#pragma unroll
  for (int e2 = 0; e2 < 8; ++e2) p[e2] = 0.f;
#pragma unroll
  for (int i = 0; i < 16; ++i) {
    int j = lane + (i << 6);
    float xv = xr[j];
    const float4* wr = (const float4*)(wg + j * 8);
    float4 a = wr[0], b = wr[1];
    p[0] += xv * a.x; p[1] += xv * a.y; p[2] += xv * a.z; p[3] += xv * a.w;
    p[4] += xv * b.x; p[5] += xv * b.y; p[6] += xv * b.z; p[7] += xv * b.w;
  }
#pragma unroll
  for (int off = 32; off > 0; off >>= 1)
#pragma unroll
    for (int e2 = 0; e2 < 8; ++e2) p[e2] += __shfl_xor(p[e2], off);
  __shared__ float smG[4][8];
  if (lane == 0) {
    float mx = p[0]; int am = 0;
#pragma unroll
    for (int e2 = 1; e2 < 8; ++e2) if (p[e2] > mx) { mx = p[e2]; am = e2; }
    float s = 0.f, g2[8];
#pragma unroll
    for (int e2 = 0; e2 < 8; ++e2) { g2[e2] = __expf(p[e2] - mx); s += g2[e2]; }
    float inv = 1.f / s;
    idx[t] = am;
    gate[t] = g2[am] * inv;
#pragma unroll
    for (int e2 = 0; e2 < 8; ++e2) smG[w][e2] = g2[e2] * inv;
  }
  __syncthreads();
  if (tid < 8)
    meP[blockIdx.x * 8 + tid] = smG[0][tid] + smG[1][tid] + smG[2][tid] + smG[3][tid];
}

// ------------- scan: per-expert cumulative position + l_aux -------------
__global__ __launch_bounds__(512) void scan_kernel(
    const int* __restrict__ idx, int* __restrict__ pos, int* __restrict__ smap,
    const float* __restrict__ meP, int nblkG, float* __restrict__ laux_out) {
  int tid = threadIdx.x, lane = tid & 63, e = tid >> 6;
  int running = 0;
  for (int c = 0; c < Tt; c += 64) {
    int mi = idx[c + lane];
    bool pr = (mi == e);
    unsigned long long m = __ballot(pr);
    int p = running + __popcll(m & ((1ull << lane) - 1ull));
    if (pr) {
      pos[c + lane] = p;
      if (p < CAP) smap[e * CAP + p] = c + lane;
    }
    running += (int)__popcll(m);
  }
  __shared__ int scnt[8];
  __shared__ float smesum[8];
  __shared__ float red[512];
  if (lane == 0) scnt[e] = running;
  float part = 0.f;
  int ee = tid & 7, b0 = tid >> 3;
  for (int b = b0; b < nblkG; b += 64) part += meP[b * 8 + ee];
  red[tid] = part;
  __syncthreads();
  if (tid < 8) {
    float s = 0.f;
    for (int i = 0; i < 64; ++i) s += red[i * 8 + tid];
    smesum[tid] = s;
  }
  __syncthreads();
  if (tid == 0) {
    float l = 0.f;
    for (int q = 0; q < 8; ++q) l += smesum[q] * (float)scnt[q];
    laux_out[0] = l * 8.0f / ((float)Tt * (float)Tt);
  }
}

// ------------- transpose + cast fp32 -> bf16 (B^T weight layout) -------------
__global__ __launch_bounds__(256) void transpose_cast(
    const float* __restrict__ src, unsigned short* __restrict__ dst, int R, int Cn) {
  __shared__ float tile[64][65];
  int e = blockIdx.z;
  const float* s = src + (size_t)e * R * Cn;
  unsigned short* d = dst + (size_t)e * R * Cn;
  int c = threadIdx.x & 63;
  int r0 = threadIdx.x >> 6;
  int rb = blockIdx.y * 64, cb = blockIdx.x * 64;
#pragma unroll
  for (int i = 0; i < 16; ++i) {
    int r = r0 + i * 4;
    tile[r][c] = s[(size_t)(rb + r) * Cn + cb + c];
  }
  __syncthreads();
#pragma unroll
  for (int i = 0; i < 16; ++i) {
    int r = r0 + i * 4;
    d[(size_t)(cb + r) * R + rb + c] = f2bf(tile[c][r]);
  }
}

// ------------- gather + cast dispatched tokens -------------
__global__ __launch_bounds__(256) void build_xg(
    const float* __restrict__ x, const int* __restrict__ smap,
    unsigned short* __restrict__ Xg) {
  int row = blockIdx.x;
  int t = smap[row];
  int j = threadIdx.x;
  float4 v = make_float4(0.f, 0.f, 0.f, 0.f);
  if (t >= 0) v = ((const float4*)(x + (size_t)t * Dd))[j];
  ushort4 o;
  o.x = f2bf(v.x); o.y = f2bf(v.y); o.z = f2bf(v.z); o.w = f2bf(v.w);
  ((ushort4*)(Xg + (size_t)row * Dd))[j] = o;
}

// ------------- 256^2-tile 4-phase bf16 MFMA GEMM (B^T), counted-vmcnt pipeline ---
// 512 threads = 8 waves (2M x 4N), per-wave 128x64 output, BK=64, dbuf LDS.
// Staging staggered per phase: {Bh0, Bh1, Ah0, Ah1}(t+1) issued at ph0..ph3 of t.
// Waits (in loads, 2/half): vmcnt(4) @ph1-end (drains Ah1(t)); vmcnt(2) @ph3-end
// (drains Bh0,Bh1,Ah0(t+1), keeps Ah1(t+1) in flight). Never 0 in steady loop.
template <int DO_GELU, int FUSE_COMBINE>
__global__ __launch_bounds__(512, 2) void gemm256_kernel(
    const unsigned short* __restrict__ A,   // [E][M][K] bf16
    const unsigned short* __restrict__ BT,  // [E][N][K] bf16
    unsigned short* __restrict__ Hout,      // [E][M][N] bf16 (GEMM1)
    const int* __restrict__ smap,           // [E][CAP] token map (GEMM2)
    const float* __restrict__ gate,         // [T]
    float* __restrict__ out,                // [T][D]
    int M, int N, int K) {
  __shared__ unsigned short lds[2][2][16384];  // [buf][A/B][256 rows x 64 k]
  int tid = threadIdx.x, lane = tid & 63, w = tid >> 6;
  int wm = w >> 2, wn = w & 3;

  // bijective XCD-aware swizzle (nwg % 8 == 0)
  int gx = gridDim.x, gy = gridDim.y;
  long gid = blockIdx.x + (long)gx * (blockIdx.y + (long)gy * blockIdx.z);
  int nT = gx * gy * (int)gridDim.z;
  int cpx = nT >> 3;
  int swz = (int)((gid & 7) * (long)cpx + (gid >> 3));
  int bn = swz % gx;
  int bm = (swz / gx) % gy;
  int e  = swz / (gx * gy);

  const unsigned short* Ab = A + ((size_t)e * M + (size_t)bm * 256) * K;
  const unsigned short* Bb = BT + ((size_t)e * N + (size_t)bn * 256) * K;

  // phys p holds logical p ^ (((p>>7)&7)<<4) (involution, both-sides swizzle)
  auto stageB = [&](const unsigned short* src, unsigned short* L, int h) {
#pragma unroll
    for (int q = 0; q < 2; ++q) {
      int p = h * 16384 + q * 8192 + tid * 16;
      int lg = p ^ (((p >> 7) & 7) << 4);
      gld16(src + (size_t)(lg >> 7) * K + ((lg & 127) >> 1),
            (unsigned short*)((char*)L + p));
    }
  };
  // A halves by phase need: h=0 -> rows [0,63]+[128,191] (mh0), h=1 -> mh1 strips
  auto stageA = [&](const unsigned short* src, unsigned short* L, int h) {
#pragma unroll
    for (int q = 0; q < 2; ++q) {
      int p = q * 16384 + h * 8192 + tid * 16;
      int lg = p ^ (((p >> 7) & 7) << 4);
      gld16(src + (size_t)(lg >> 7) * K + ((lg & 127) >> 1),
            (unsigned short*)((char*)L + p));
    }
  };
  auto frag = [&](const unsigned short* L, int row, int kc) -> bf16x8 {
    int byte = (row << 7) + (kc << 1);
    byte ^= (row & 7) << 4;
    return *(const bf16x8*)((const char*)L + byte);
  };

  f32x4 acc[2][4][4];
#pragma unroll
  for (int mh = 0; mh < 2; ++mh)
#pragma unroll
    for (int mi = 0; mi < 4; ++mi)
#pragma unroll
      for (int n = 0; n < 4; ++n) acc[mh][mi][n] = (f32x4){0.f, 0.f, 0.f, 0.f};

  auto mfma16 = [&](f32x4 (*ac)[4], const bf16x8* av, const bf16x8* bv) {
#pragma unroll
    for (int mi = 0; mi < 4; ++mi)
#pragma unroll
      for (int n = 0; n < 4; ++n)
        ac[mi][n] = __builtin_amdgcn_mfma_f32_16x16x32_bf16(av[mi], bv[n], ac[mi][n], 0, 0, 0);
  };

  int NT = K >> 6;
  int arow = wm * 128 + (lane & 15);
  int brow = wn * 64 + (lane & 15);
  int kcA = (lane >> 4) << 3;

  // prologue: tile 0 in steady-state issue order
  stageB(Bb, lds[0][1], 0);
  stageB(Bb, lds[0][1], 1);
  stageA(Ab, lds[0][0], 0);
  stageA(Ab, lds[0][0], 1);
  asm volatile("s_waitcnt vmcnt(2)" ::: "memory");
  __builtin_amdgcn_s_barrier();

  for (int t = 0; t < NT - 1; ++t) {
    const unsigned short* LA = lds[t & 1][0];
    const unsigned short* LB = lds[t & 1][1];
    unsigned short* SA = lds[(t & 1) ^ 1][0];
    unsigned short* SB = lds[(t & 1) ^ 1][1];
    const unsigned short* An = Ab + ((t + 1) << 6);
    const unsigned short* Bn = Bb + ((t + 1) << 6);
    bf16x8 a[4], b0[4], b1[4];
    // ---- ph0: ks0, mh0 ----
#pragma unroll
    for (int i = 0; i < 4; ++i) b0[i] = frag(LB, brow + i * 16, kcA);
#pragma unroll
    for (int i = 0; i < 4; ++i) a[i] = frag(LA, arow + i * 16, kcA);
    stageB(Bn, SB, 0);
    __builtin_amdgcn_s_barrier();
    asm volatile("s_waitcnt lgkmcnt(0)" ::: "memory");
    __builtin_amdgcn_sched_barrier(0);
    __builtin_amdgcn_s_setprio(1);
    mfma16(acc[0], a, b0);
    __builtin_amdgcn_s_setprio(0);
    __builtin_amdgcn_s_barrier();
    // ---- ph1: ks1, mh0 ----
#pragma unroll
    for (int i = 0; i < 4; ++i) b1[i] = frag(LB, brow + i * 16, 32 + kcA);
#pragma unroll
    for (int i = 0; i < 4; ++i) a[i] = frag(LA, arow + i * 16, 32 + kcA);
    stageB(Bn, SB, 1);
    __builtin_amdgcn_s_barrier();
    asm volatile("s_waitcnt lgkmcnt(0)" ::: "memory");
    __builtin_amdgcn_sched_barrier(0);
    __builtin_amdgcn_s_setprio(1);
    mfma16(acc[0], a, b1);
    __builtin_amdgcn_s_setprio(0);
    asm volatile("s_waitcnt vmcnt(4)" ::: "memory");
    __builtin_amdgcn_s_barrier();
    // ---- ph2: ks0, mh1 ----
#pragma unroll
    for (int i = 0; i < 4; ++i) a[i] = frag(LA, arow + 64 + i * 16, kcA);
    stageA(An, SA, 0);
    __builtin_amdgcn_s_barrier();
    asm volatile("s_waitcnt lgkmcnt(0)" ::: "memory");
    __builtin_amdgcn_sched_barrier(0);
    __builtin_amdgcn_s_setprio(1);
    mfma16(acc[1], a, b0);
    __builtin_amdgcn_s_setprio(0);
    __builtin_amdgcn_s_barrier();
    // ---- ph3: ks1, mh1 ----
#pragma unroll
    for (int i = 0; i < 4; ++i) a[i] = frag(LA, arow + 64 + i * 16, 32 + kcA);
    stageA(An, SA, 1);
    __builtin_amdgcn_s_barrier();
    asm volatile("s_waitcnt lgkmcnt(0)" ::: "memory");
    __builtin_amdgcn_sched_barrier(0);
    __builtin_amdgcn_s_setprio(1);
    mfma16(acc[1], a, b1);
    __builtin_amdgcn_s_setprio(0);
    asm volatile("s_waitcnt vmcnt(2)" ::: "memory");
    __builtin_amdgcn_s_barrier();
  }

  // ---- final tile (no prefetch) ----
  {
    int t = NT - 1;
    const unsigned short* LA = lds[t & 1][0];
    const unsigned short* LB = lds[t & 1][1];
    bf16x8 a[4], b0[4], b1[4];
#pragma unroll
    for (int i = 0; i < 4; ++i) b0[i] = frag(LB, brow + i * 16, kcA);
#pragma unroll
    for (int i = 0; i < 4; ++i) a[i] = frag(LA, arow + i * 16, kcA);
    __builtin_amdgcn_s_barrier();
    asm volatile("s_waitcnt lgkmcnt(0)" ::: "memory");
    __builtin_amdgcn_sched_barrier(0);
    __builtin_amdgcn_s_setprio(1);
    mfma16(acc[0], a, b0);
    __builtin_amdgcn_s_setprio(0);
    __builtin_amdgcn_s_barrier();
#pragma unroll
    for (int i = 0; i < 4; ++i) b1[i] = frag(LB, brow + i * 16, 32 + kcA);
#pragma unroll
    for (int i = 0; i < 4; ++i) a[i] = frag(LA, arow + i * 16, 32 + kcA);
    __builtin_amdgcn_s_barrier();
    asm volatile("s_waitcnt lgkmcnt(0)" ::: "memory");
    __builtin_amdgcn_sched_barrier(0);
    __builtin_amdgcn_s_setprio(1);
    mfma16(acc[0], a, b1);
    __builtin_amdgcn_s_setprio(0);
    asm volatile("s_waitcnt vmcnt(0)" ::: "memory");
    __builtin_amdgcn_s_barrier();
#pragma unroll
    for (int i = 0; i < 4; ++i) a[i] = frag(LA, arow + 64 + i * 16, kcA);
    asm volatile("s_waitcnt lgkmcnt(0)" ::: "memory");
    __builtin_amdgcn_sched_barrier(0);
    __builtin_amdgcn_s_setprio(1);
    mfma16(acc[1], a, b0);
    __builtin_amdgcn_s_setprio(0);
#pragma unroll
    for (int i = 0; i < 4; ++i) a[i] = frag(LA, arow + 64 + i * 16, 32 + kcA);
    asm volatile("s_waitcnt lgkmcnt(0)" ::: "memory");
    __builtin_amdgcn_sched_barrier(0);
    __builtin_amdgcn_s_setprio(1);
    mfma16(acc[1], a, b1);
    __builtin_amdgcn_s_setprio(0);
  }

  // ---- epilogue ----
  int r0 = bm * 256 + wm * 128;
  int c0 = bn * 256 + wn * 64;
#pragma unroll
  for (int mh = 0; mh < 2; ++mh)
#pragma unroll
    for (int mi = 0; mi < 4; ++mi) {
      int rowb = r0 + mh * 64 + mi * 16 + ((lane >> 4) << 2);
#pragma unroll
      for (int r = 0; r < 4; ++r) {
        int row = rowb + r;
        if (DO_GELU) {
#pragma unroll
          for (int n = 0; n < 4; ++n) {
            int col = c0 + n * 16 + (lane & 15);
            Hout[((size_t)e * M + row) * N + col] = f2bf(gelu_tanh(acc[mh][mi][n][r]));
          }
        }
        if (FUSE_COMBINE) {
          int tkn = smap[e * CAP + row];
          if (tkn >= 0) {
            float g = gate[tkn];
#pragma unroll
            for (int n = 0; n < 4; ++n) {
              int col = c0 + n * 16 + (lane & 15);
              out[(size_t)tkn * Dd + col] = acc[mh][mi][n][r] * g;
            }
          }
        }
      }
    }
}

extern "C" void kernel_launch(void* const* d_in, const int* in_sizes, int n_in,
                              void* d_out, int out_size, void* d_ws, size_t ws_size,
                              hipStream_t stream) {
  const float* x  = (const float*)d_in[0];
  const float* wg = (const float*)d_in[1];
  const float* w1 = (const float*)d_in[2];
  const float* w2 = (const float*)d_in[3];
  float* out = (float*)d_out;

  char* ws = (char*)d_ws;
  int*   idx  = (int*)(ws + 0);
  int*   pos  = (int*)(ws + 65536);
  float* gate = (float*)(ws + 131072);
  float* meP  = (float*)(ws + 196608);
  int*   smap = (int*)(ws + 327680);
  unsigned short* Xg  = (unsigned short*)(ws + 393216ull);
  unsigned short* W1T = (unsigned short*)(ws + 33947648ull);
  unsigned short* W2T = (unsigned short*)(ws + 101056512ull);
  unsigned short* H   = (unsigned short*)(ws + 168165376ull);

  hipMemsetAsync(out, 0, (size_t)Tt * Dd * sizeof(float), stream);
  hipMemsetAsync(smap, 0xFF, Ee * CAP * 4, stream);
  gating_kernel<<<Tt / 4, 256, 0, stream>>>(x, wg, idx, gate, meP);
  scan_kernel<<<1, 512, 0, stream>>>(idx, pos, smap, meP, Tt / 4,
                                     out + (size_t)Tt * Dd);
  transpose_cast<<<dim3(DFFf / 64, Dd / 64, Ee), 256, 0, stream>>>(w1, W1T, Dd, DFFf);
  transpose_cast<<<dim3(Dd / 64, DFFf / 64, Ee), 256, 0, stream>>>(w2, W2T, DFFf, Dd);
  build_xg<<<Ee * CAP, 256, 0, stream>>>(x, smap, Xg);
  gemm256_kernel<1, 0><<<dim3(DFFf / 256, CAP / 256, Ee), 512, 0, stream>>>(
      Xg, W1T, H, nullptr, nullptr, nullptr, CAP, DFFf, Dd);
  gemm256_kernel<0, 1><<<dim3(Dd / 256, CAP / 256, Ee), 512, 0, stream>>>(
      H, W2T, nullptr, smap, gate, out, CAP, Dd, DFFf);
}

// Round 4
// 488.968 us; speedup vs baseline: 1.5159x; 1.0908x over previous
//
#include <hip/hip_runtime.h>
#include <hip/hip_bf16.h>

#define Tt   16384
#define Dd   1024
#define Ee   8
#define CAP  2048
#define DFFf 4096

typedef __attribute__((ext_vector_type(8))) short bf16x8;
typedef __attribute__((ext_vector_type(4))) float f32x4;

__device__ __forceinline__ unsigned short f2bf(float f) {
  union { float f; unsigned u; } v; v.f = f;
  unsigned r = (v.u + 0x7FFFu + ((v.u >> 16) & 1u)) >> 16;
  return (unsigned short)r;
}

__device__ __forceinline__ float gelu_tanh(float x) {
  float z = 0.7978845608028654f * (x + 0.044715f * x * x * x);
  float az = fabsf(z);
  float t = __expf(-2.0f * az);
  float th = (1.0f - t) / (1.0f + t);
  th = (z < 0.0f) ? -th : th;
  return 0.5f * x * (1.0f + th);
}

__device__ __forceinline__ void gld16(const unsigned short* g, unsigned short* l) {
  __builtin_amdgcn_global_load_lds(
      (const __attribute__((address_space(1))) void*)g,
      (__attribute__((address_space(3))) void*)l,
      16, 0, 0);
}

template <int IMM>
__device__ __forceinline__ bf16x8 dsr(unsigned a) {
  bf16x8 r;
  asm volatile("ds_read_b128 %0, %1 offset:%c2" : "=v"(r) : "v"(a), "i"(IMM));
  return r;
}
#define LGKM(N) asm volatile("s_waitcnt lgkmcnt(" #N ")" ::: "memory")
#define VMCNT(N) asm volatile("s_waitcnt vmcnt(" #N ")" ::: "memory")

// ---------------- gating: logits fp32, softmax, argmax ----------------
__global__ __launch_bounds__(256) void gating_kernel(
    const float* __restrict__ x, const float* __restrict__ wg,
    int* __restrict__ idx, float* __restrict__ gate, float* __restrict__ meP) {
  int tid = threadIdx.x, lane = tid & 63, w = tid >> 6;
  int t = blockIdx.x * 4 + w;
  const float* xr = x + (size_t)t * Dd;
  float p[8];
#pragma unroll
  for (int e2 = 0; e2 < 8; ++e2) p[e2] = 0.f;
#pragma unroll
  for (int i = 0; i < 16; ++i) {
    int j = lane + (i << 6);
    float xv = xr[j];
    const float4* wr = (const float4*)(wg + j * 8);
    float4 a = wr[0], b = wr[1];
    p[0] += xv * a.x; p[1] += xv * a.y; p[2] += xv * a.z; p[3] += xv * a.w;
    p[4] += xv * b.x; p[5] += xv * b.y; p[6] += xv * b.z; p[7] += xv * b.w;
  }
#pragma unroll
  for (int off = 32; off > 0; off >>= 1)
#pragma unroll
    for (int e2 = 0; e2 < 8; ++e2) p[e2] += __shfl_xor(p[e2], off);
  __shared__ float smG[4][8];
  if (lane == 0) {
    float mx = p[0]; int am = 0;
#pragma unroll
    for (int e2 = 1; e2 < 8; ++e2) if (p[e2] > mx) { mx = p[e2]; am = e2; }
    float s = 0.f, g2[8];
#pragma unroll
    for (int e2 = 0; e2 < 8; ++e2) { g2[e2] = __expf(p[e2] - mx); s += g2[e2]; }
    float inv = 1.f / s;
    idx[t] = am;
    gate[t] = g2[am] * inv;
#pragma unroll
    for (int e2 = 0; e2 < 8; ++e2) smG[w][e2] = g2[e2] * inv;
  }
  __syncthreads();
  if (tid < 8)
    meP[blockIdx.x * 8 + tid] = smG[0][tid] + smG[1][tid] + smG[2][tid] + smG[3][tid];
}

// ------------- scan: per-expert cumulative position + l_aux -------------
__global__ __launch_bounds__(512) void scan_kernel(
    const int* __restrict__ idx, int* __restrict__ pos, int* __restrict__ smap,
    const float* __restrict__ meP, int nblkG, float* __restrict__ laux_out) {
  int tid = threadIdx.x, lane = tid & 63, e = tid >> 6;
  int running = 0;
  for (int c = 0; c < Tt; c += 256) {
    int m0 = idx[c + lane];
    int m1 = idx[c + 64 + lane];
    int m2 = idx[c + 128 + lane];
    int m3 = idx[c + 192 + lane];
#define RND(mv, base) { \
    unsigned long long mm = __ballot(mv == e); \
    int p = running + __popcll(mm & ((1ull << lane) - 1ull)); \
    if (mv == e) { pos[(base) + lane] = p; if (p < CAP) smap[e * CAP + p] = (base) + lane; } \
    running += (int)__popcll(mm); }
    RND(m0, c) RND(m1, c + 64) RND(m2, c + 128) RND(m3, c + 192)
#undef RND
  }
  __shared__ int scnt[8];
  __shared__ float smesum[8];
  __shared__ float red[512];
  if (lane == 0) scnt[e] = running;
  float part = 0.f;
  int ee = tid & 7, b0 = tid >> 3;
  for (int b = b0; b < nblkG; b += 64) part += meP[b * 8 + ee];
  red[tid] = part;
  __syncthreads();
  if (tid < 8) {
    float s = 0.f;
    for (int i = 0; i < 64; ++i) s += red[i * 8 + tid];
    smesum[tid] = s;
  }
  __syncthreads();
  if (tid == 0) {
    float l = 0.f;
    for (int q = 0; q < 8; ++q) l += smesum[q] * (float)scnt[q];
    laux_out[0] = l * 8.0f / ((float)Tt * (float)Tt);
  }
}

// ------------- zero dropped-token output rows -------------
__global__ __launch_bounds__(256) void zero_dropped(
    const int* __restrict__ pos, float* __restrict__ out) {
  int t = blockIdx.x;
  if (pos[t] < CAP) return;
  ((float4*)(out + (size_t)t * Dd))[threadIdx.x] = make_float4(0.f, 0.f, 0.f, 0.f);
}

// ------------- transpose + cast fp32 -> bf16 (B^T weight layout) -------------
__global__ __launch_bounds__(256) void transpose_cast(
    const float* __restrict__ src, unsigned short* __restrict__ dst, int R, int Cn) {
  __shared__ float tile[64][65];
  int e = blockIdx.z;
  const float* s = src + (size_t)e * R * Cn;
  unsigned short* d = dst + (size_t)e * R * Cn;
  int c = threadIdx.x & 63;
  int r0 = threadIdx.x >> 6;
  int rb = blockIdx.y * 64, cb = blockIdx.x * 64;
#pragma unroll
  for (int i = 0; i < 16; ++i) {
    int r = r0 + i * 4;
    tile[r][c] = s[(size_t)(rb + r) * Cn + cb + c];
  }
  __syncthreads();
#pragma unroll
  for (int i = 0; i < 16; ++i) {
    int r = r0 + i * 4;
    d[(size_t)(cb + r) * R + rb + c] = f2bf(tile[c][r]);
  }
}

// ------------- gather + cast dispatched tokens -------------
__global__ __launch_bounds__(256) void build_xg(
    const float* __restrict__ x, const int* __restrict__ smap,
    unsigned short* __restrict__ Xg) {
  int row = blockIdx.x;
  int t = smap[row];
  int j = threadIdx.x;
  float4 v = make_float4(0.f, 0.f, 0.f, 0.f);
  if (t >= 0) v = ((const float4*)(x + (size_t)t * Dd))[j];
  ushort4 o;
  o.x = f2bf(v.x); o.y = f2bf(v.y); o.z = f2bf(v.z); o.w = f2bf(v.w);
  ((ushort4*)(Xg + (size_t)row * Dd))[j] = o;
}

// ------------- 256^2-tile bf16 MFMA GEMM (B^T), fragment-pipelined ----------
// 8 waves (2M x 4N), per-wave 128x64, BK=64, full dbuf LDS, 1 barrier/K-tile.
// Frag groups G0{b0,a-mh0ks0}(8) G1{b1,a-mh0ks1}(8) G2{a-mh1ks0}(4) G3(4);
// counted lgkm waits 8/4/4/0 overlap ds_read with MFMA. vmcnt(0) once per tile.
template <int DO_GELU, int FUSE_COMBINE>
__global__ __launch_bounds__(512, 2) void gemm256_kernel(
    const unsigned short* __restrict__ A,   // [E][M][K] bf16
    const unsigned short* __restrict__ BT,  // [E][N][K] bf16
    unsigned short* __restrict__ Hout,      // [E][M][N] bf16 (GEMM1)
    const int* __restrict__ smap,           // [E][CAP] token map (GEMM2)
    const float* __restrict__ gate,         // [T]
    float* __restrict__ out,                // [T][D]
    int M, int N, int K) {
  __shared__ unsigned short lds[2][2][16384];  // [buf][A/B][256 rows x 64 k]
  int tid = threadIdx.x, lane = tid & 63, w = tid >> 6;
  int wm = w >> 2, wn = w & 3;

  // bijective XCD-aware swizzle (nwg % 8 == 0)
  int gx = gridDim.x, gy = gridDim.y;
  long gid = blockIdx.x + (long)gx * (blockIdx.y + (long)gy * blockIdx.z);
  int nT = gx * gy * (int)gridDim.z;
  int cpx = nT >> 3;
  int swz = (int)((gid & 7) * (long)cpx + (gid >> 3));
  int bn = swz % gx;
  int bm = (swz / gx) % gy;
  int e  = swz / (gx * gy);

  const unsigned short* Ab = A + ((size_t)e * M + (size_t)bm * 256) * K;
  const unsigned short* Bb = BT + ((size_t)e * N + (size_t)bn * 256) * K;

  // phys p holds logical p ^ (((p>>7)&7)<<4) (involution, both-sides swizzle)
  auto stageB = [&](const unsigned short* src, unsigned short* L, int h) {
#pragma unroll
    for (int q = 0; q < 2; ++q) {
      int p = h * 16384 + q * 8192 + tid * 16;
      int lg = p ^ (((p >> 7) & 7) << 4);
      gld16(src + (size_t)(lg >> 7) * K + ((lg & 127) >> 1),
            (unsigned short*)((char*)L + p));
    }
  };
  auto stageA = [&](const unsigned short* src, unsigned short* L, int h) {
#pragma unroll
    for (int q = 0; q < 2; ++q) {
      int p = q * 16384 + h * 8192 + tid * 16;
      int lg = p ^ (((p >> 7) & 7) << 4);
      gld16(src + (size_t)(lg >> 7) * K + ((lg & 127) >> 1),
            (unsigned short*)((char*)L + p));
    }
  };

  f32x4 acc[2][4][4];
#pragma unroll
  for (int mh = 0; mh < 2; ++mh)
#pragma unroll
    for (int mi = 0; mi < 4; ++mi)
#pragma unroll
      for (int n = 0; n < 4; ++n) acc[mh][mi][n] = (f32x4){0.f, 0.f, 0.f, 0.f};

  auto mfma16 = [&](f32x4 (*ac)[4], const bf16x8* av, const bf16x8* bv) {
#pragma unroll
    for (int mi = 0; mi < 4; ++mi)
#pragma unroll
      for (int n = 0; n < 4; ++n)
        ac[mi][n] = __builtin_amdgcn_mfma_f32_16x16x32_bf16(av[mi], bv[n], ac[mi][n], 0, 0, 0);
  };

  // per-wave LDS fragment base addresses (u32 LDS byte addr), swizzle folded in
  unsigned lbase = (unsigned)(size_t)(__attribute__((address_space(3))) unsigned short*)&lds[0][0][0];
  int arow = wm * 128 + (lane & 15);
  int brow = wn * 64 + (lane & 15);
  unsigned kc2 = (unsigned)(((lane >> 4) << 3) << 1);  // k byte offset 0/16/32/48
  unsigned swA = (unsigned)((arow & 7) << 4), swB = (unsigned)((brow & 7) << 4);
  unsigned ak0 = lbase + ((((unsigned)arow << 7) + kc2) ^ swA);
  unsigned ak1 = lbase + ((((unsigned)arow << 7) + 64 + kc2) ^ swA);
  unsigned bk0 = lbase + 32768u + ((((unsigned)brow << 7) + kc2) ^ swB);
  unsigned bk1 = lbase + 32768u + ((((unsigned)brow << 7) + 64 + kc2) ^ swB);

  int NT = K >> 6;
  // prologue: stage tile 0 into buf0, then issue G0
  stageB(Bb, lds[0][1], 0); stageB(Bb, lds[0][1], 1);
  stageA(Ab, lds[0][0], 0); stageA(Ab, lds[0][0], 1);
  VMCNT(0);
  __builtin_amdgcn_s_barrier();
  bf16x8 a0[4], a1[4], a2[4], a3[4], b0[4], b1[4];
  b0[0] = dsr<0>(bk0); b0[1] = dsr<2048>(bk0); b0[2] = dsr<4096>(bk0); b0[3] = dsr<6144>(bk0);
  a0[0] = dsr<0>(ak0); a0[1] = dsr<2048>(ak0); a0[2] = dsr<4096>(ak0); a0[3] = dsr<6144>(ak0);

  for (int t = 0; t < NT; ++t) {
    bool pf = (t + 1 < NT);
    unsigned short* SA = lds[(t & 1) ^ 1][0];
    unsigned short* SB = lds[(t & 1) ^ 1][1];
    const unsigned short* An = Ab + ((t + 1) << 6);
    const unsigned short* Bn = Bb + ((t + 1) << 6);
    // ---- ph0: issue G1, stage B(t+1); wait G0; MFMA a0xb0 -> acc0 ----
    b1[0] = dsr<0>(bk1); b1[1] = dsr<2048>(bk1); b1[2] = dsr<4096>(bk1); b1[3] = dsr<6144>(bk1);
    a1[0] = dsr<0>(ak1); a1[1] = dsr<2048>(ak1); a1[2] = dsr<4096>(ak1); a1[3] = dsr<6144>(ak1);
    if (pf) { stageB(Bn, SB, 0); stageB(Bn, SB, 1); }
    LGKM(8);
    __builtin_amdgcn_sched_barrier(0);
    __builtin_amdgcn_s_setprio(1);
    mfma16(acc[0], a0, b0);
    __builtin_amdgcn_s_setprio(0);
    // ---- ph1: issue G2, stage A(t+1); wait G1; MFMA a1xb1 -> acc0 ----
    a2[0] = dsr<8192>(ak0); a2[1] = dsr<10240>(ak0); a2[2] = dsr<12288>(ak0); a2[3] = dsr<14336>(ak0);
    if (pf) { stageA(An, SA, 0); stageA(An, SA, 1); }
    LGKM(4);
    __builtin_amdgcn_sched_barrier(0);
    __builtin_amdgcn_s_setprio(1);
    mfma16(acc[0], a1, b1);
    __builtin_amdgcn_s_setprio(0);
    // ---- ph2: issue G3; wait G2; MFMA a2xb0 -> acc1 ----
    a3[0] = dsr<8192>(ak1); a3[1] = dsr<10240>(ak1); a3[2] = dsr<12288>(ak1); a3[3] = dsr<14336>(ak1);
    LGKM(4);
    __builtin_amdgcn_sched_barrier(0);
    __builtin_amdgcn_s_setprio(1);
    mfma16(acc[1], a2, b0);
    __builtin_amdgcn_s_setprio(0);
    // ---- ph3: wait G3; MFMA a3xb1 -> acc1; tile swap ----
    LGKM(0);
    __builtin_amdgcn_sched_barrier(0);
    __builtin_amdgcn_s_setprio(1);
    mfma16(acc[1], a3, b1);
    __builtin_amdgcn_s_setprio(0);
    if (pf) {
      VMCNT(0);
      __builtin_amdgcn_s_barrier();
      ak0 ^= 65536u; ak1 ^= 65536u; bk0 ^= 65536u; bk1 ^= 65536u;
      b0[0] = dsr<0>(bk0); b0[1] = dsr<2048>(bk0); b0[2] = dsr<4096>(bk0); b0[3] = dsr<6144>(bk0);
      a0[0] = dsr<0>(ak0); a0[1] = dsr<2048>(ak0); a0[2] = dsr<4096>(ak0); a0[3] = dsr<6144>(ak0);
    }
  }

  // ---- epilogue ----
  int r0 = bm * 256 + wm * 128;
  int c0 = bn * 256 + wn * 64;
#pragma unroll
  for (int mh = 0; mh < 2; ++mh)
#pragma unroll
    for (int mi = 0; mi < 4; ++mi) {
      int rowb = r0 + mh * 64 + mi * 16 + ((lane >> 4) << 2);
#pragma unroll
      for (int r = 0; r < 4; ++r) {
        int row = rowb + r;
        if (DO_GELU) {
#pragma unroll
          for (int n = 0; n < 4; ++n) {
            int col = c0 + n * 16 + (lane & 15);
            Hout[((size_t)e * M + row) * N + col] = f2bf(gelu_tanh(acc[mh][mi][n][r]));
          }
        }
        if (FUSE_COMBINE) {
          int tkn = smap[e * CAP + row];
          if (tkn >= 0) {
            float g = gate[tkn];
#pragma unroll
            for (int n = 0; n < 4; ++n) {
              int col = c0 + n * 16 + (lane & 15);
              out[(size_t)tkn * Dd + col] = acc[mh][mi][n][r] * g;
            }
          }
        }
      }
    }
}

extern "C" void kernel_launch(void* const* d_in, const int* in_sizes, int n_in,
                              void* d_out, int out_size, void* d_ws, size_t ws_size,
                              hipStream_t stream) {
  const float* x  = (const float*)d_in[0];
  const float* wg = (const float*)d_in[1];
  const float* w1 = (const float*)d_in[2];
  const float* w2 = (const float*)d_in[3];
  float* out = (float*)d_out;

  char* ws = (char*)d_ws;
  int*   idx  = (int*)(ws + 0);
  int*   pos  = (int*)(ws + 65536);
  float* gate = (float*)(ws + 131072);
  float* meP  = (float*)(ws + 196608);
  int*   smap = (int*)(ws + 327680);
  unsigned short* Xg  = (unsigned short*)(ws + 393216ull);
  unsigned short* W1T = (unsigned short*)(ws + 33947648ull);
  unsigned short* W2T = (unsigned short*)(ws + 101056512ull);
  unsigned short* H   = (unsigned short*)(ws + 168165376ull);

  hipMemsetAsync(smap, 0xFF, Ee * CAP * 4, stream);
  gating_kernel<<<Tt / 4, 256, 0, stream>>>(x, wg, idx, gate, meP);
  scan_kernel<<<1, 512, 0, stream>>>(idx, pos, smap, meP, Tt / 4,
                                     out + (size_t)Tt * Dd);
  zero_dropped<<<Tt, 256, 0, stream>>>(pos, out);
  transpose_cast<<<dim3(DFFf / 64, Dd / 64, Ee), 256, 0, stream>>>(w1, W1T, Dd, DFFf);
  transpose_cast<<<dim3(Dd / 64, DFFf / 64, Ee), 256, 0, stream>>>(w2, W2T, DFFf, Dd);
  build_xg<<<Ee * CAP, 256, 0, stream>>>(x, smap, Xg);
  gemm256_kernel<1, 0><<<dim3(DFFf / 256, CAP / 256, Ee), 512, 0, stream>>>(
      Xg, W1T, H, nullptr, nullptr, nullptr, CAP, DFFf, Dd);
  gemm256_kernel<0, 1><<<dim3(Dd / 256, CAP / 256, Ee), 512, 0, stream>>>(
      H, W2T, nullptr, smap, gate, out, CAP, Dd, DFFf);
}